// Round 16
// baseline (439.274 us; speedup 1.0000x reference)
//
#include <hip/hip_runtime.h>
#include <stdint.h>

#define NPTS 131072

// ---------- helpers (XLA:GPU contraction semantics: fma-fused) ----------

__device__ __forceinline__ float cubw(float t) {
#pragma clang fp contract(off)
  float at = fabsf(t);
  if (at <= 1.0f) {
    float u = fmaf(1.25f, at, -2.25f);
    u = u * at;
    return fmaf(u, at, 1.0f);
  } else if (at < 2.0f) {
    float u = at - 5.0f;
    u = fmaf(u, at, 8.0f);
    u = fmaf(u, at, -4.0f);
    return u * -0.75f;
  }
  return 0.0f;
}

__device__ __forceinline__ float quant_frac(int t) {
#pragma clang fp contract(off)
  return (float)(t + 1) * 0.015625f;
}

__device__ __forceinline__ float grid_val(int i) {
#pragma clang fp contract(off)
  return (float)i * (1.0f / 63.0f);
}

__device__ __forceinline__ float jax_quantile_lerp(float vlo, float vhi, float q) {
#pragma clang fp contract(off)
  float lowf = floorf(q);
  float highf = ceilf(q);
  float hw = q - lowf;
  float lw = highf - q;
  float bh = vhi * hw;
  return fmaf(vlo, lw, bh);
}

__device__ __forceinline__ float bilerp1(float a, float b, float w) {
#pragma clang fp contract(off)
  float omw = 1.0f - w;
  float bw = b * w;
  return fmaf(a, omw, bw);
}

template <int NB>
__device__ __forceinline__ unsigned long long match_mask(uint32_t d) {
  unsigned long long m = ~0ull;
#pragma unroll
  for (int i = 0; i < NB; ++i) {
    unsigned long long bal = __ballot((int)((d >> i) & 1u));
    m &= ((d >> i) & 1u) ? bal : ~bal;
  }
  return m;
}

// adjusted level-1 key: u(fl(x + 8b)) - u(8b)  (order-preserving; <=2^20 for b>=1, <2^30 for b=0)
__device__ __forceinline__ uint32_t l1key(const float* coords, int batch, int idx) {
#pragma clang fp contract(off)
  float off = (float)(8 * batch);
  float c = coords[(size_t)(batch * 2) * NPTS + idx] + off;
  return __float_as_uint(c) - __float_as_uint(off);
}

// ---------- 11-bit radix passes ----------

__global__ __launch_bounds__(256) void k_rh11_0(const float* __restrict__ coords,
                                                uint32_t* __restrict__ hist) {
  __shared__ uint32_t h[2048];
  int tid = threadIdx.x;
  int batch = blockIdx.x >> 5, blk = blockIdx.x & 31;
  for (int i = tid; i < 2048; i += 256) h[i] = 0;
  __syncthreads();
  for (int r = 0; r < 16; ++r) {
    uint32_t d = l1key(coords, batch, blk * 4096 + r * 256 + tid) & 2047u;
    atomicAdd(&h[d], 1u);
  }
  __syncthreads();
  for (int i = tid; i < 2048; i += 256)
    hist[((size_t)batch * 2048 + i) * 32 + blk] = h[i];
}

__global__ __launch_bounds__(256) void k_rh11(const uint32_t* __restrict__ in,
                                              uint32_t* __restrict__ hist, int shift) {
  __shared__ uint32_t h[2048];
  int tid = threadIdx.x;
  int batch = blockIdx.x >> 5, blk = blockIdx.x & 31;
  for (int i = tid; i < 2048; i += 256) h[i] = 0;
  __syncthreads();
  const uint32_t* keys = in + (size_t)batch * NPTS + (size_t)blk * 4096;
  for (int r = 0; r < 16; ++r) {
    uint32_t d = (keys[r * 256 + tid] >> shift) & 2047u;
    atomicAdd(&h[d], 1u);
  }
  __syncthreads();
  for (int i = tid; i < 2048; i += 256)
    hist[((size_t)batch * 2048 + i) * 32 + blk] = h[i];
}

__global__ __launch_bounds__(256) void k_scan(uint32_t* __restrict__ buf, int len) {
  __shared__ uint32_t tot[256];
  int batch = blockIdx.x, tid = threadIdx.x;
  int per = len >> 8;
  uint32_t* p = buf + (size_t)batch * len + (size_t)tid * per;
  uint32_t s = 0;
  for (int i = 0; i < per; ++i) s += p[i];
  tot[tid] = s;
  __syncthreads();
  if (tid == 0) {
    uint32_t run = 0;
    for (int i = 0; i < 256; ++i) { uint32_t t = tot[i]; tot[i] = run; run += t; }
  }
  __syncthreads();
  uint32_t run = tot[tid];
  for (int i = 0; i < per; ++i) { uint32_t t = p[i]; p[i] = run; run += t; }
}

__global__ __launch_bounds__(256) void k_rs11_0(const float* __restrict__ coords,
                                                uint32_t* __restrict__ out,
                                                const uint32_t* __restrict__ base) {
  __shared__ uint32_t whist[4 * 2048];
  int tid = threadIdx.x;
  int wv = tid >> 6, lane = tid & 63;
  int batch = blockIdx.x >> 5, blk = blockIdx.x & 31;
  size_t batchbase = (size_t)batch * NPTS;

  for (int i = tid; i < 4 * 2048; i += 256) whist[i] = 0;
  __syncthreads();

  uint32_t keyv[16], posv[16];
#pragma unroll
  for (int r = 0; r < 16; ++r) {
    uint32_t key = l1key(coords, batch, blk * 4096 + wv * 1024 + r * 64 + lane);
    uint32_t d = key & 2047u;
    unsigned long long m = match_mask<11>(d);
    unsigned long long below = m & ((1ull << lane) - 1ull);
    uint32_t rank = (uint32_t)__popcll(below);
    uint32_t cnt = (uint32_t)__popcll(m);
    uint32_t bse = whist[wv * 2048 + d];
    if (below == 0ull) whist[wv * 2048 + d] = bse + cnt;
    keyv[r] = key;
    posv[r] = bse + rank;
  }
  __syncthreads();
  for (int i = tid; i < 2048; i += 256) {
    uint32_t a0 = whist[i], a1 = whist[2048 + i], a2 = whist[4096 + i];
    whist[i] = 0;
    whist[2048 + i] = a0;
    whist[4096 + i] = a0 + a1;
    whist[6144 + i] = a0 + a1 + a2;
  }
  __syncthreads();
  const uint32_t* bb = base + (size_t)batch * 65536;
#pragma unroll
  for (int r = 0; r < 16; ++r) {
    uint32_t key = keyv[r];
    uint32_t d = key & 2047u;
    uint32_t pos = bb[d * 32 + blk] + whist[wv * 2048 + d] + posv[r];
    out[batchbase + pos] = key;
  }
}

__global__ __launch_bounds__(256) void k_rs11(const uint32_t* __restrict__ in,
                                              uint32_t* __restrict__ out,
                                              const uint32_t* __restrict__ base, int shift) {
  __shared__ uint32_t whist[4 * 2048];
  int tid = threadIdx.x;
  int wv = tid >> 6, lane = tid & 63;
  int batch = blockIdx.x >> 5, blk = blockIdx.x & 31;
  size_t batchbase = (size_t)batch * NPTS;
  const uint32_t* src = in + batchbase + (size_t)blk * 4096 + (size_t)wv * 1024;

  for (int i = tid; i < 4 * 2048; i += 256) whist[i] = 0;
  __syncthreads();

  uint32_t keyv[16], posv[16];
#pragma unroll
  for (int r = 0; r < 16; ++r) {
    uint32_t key = src[r * 64 + lane];
    uint32_t d = (key >> shift) & 2047u;
    unsigned long long m = match_mask<11>(d);
    unsigned long long below = m & ((1ull << lane) - 1ull);
    uint32_t rank = (uint32_t)__popcll(below);
    uint32_t cnt = (uint32_t)__popcll(m);
    uint32_t bse = whist[wv * 2048 + d];
    if (below == 0ull) whist[wv * 2048 + d] = bse + cnt;
    keyv[r] = key;
    posv[r] = bse + rank;
  }
  __syncthreads();
  for (int i = tid; i < 2048; i += 256) {
    uint32_t a0 = whist[i], a1 = whist[2048 + i], a2 = whist[4096 + i];
    whist[i] = 0;
    whist[2048 + i] = a0;
    whist[4096 + i] = a0 + a1;
    whist[6144 + i] = a0 + a1 + a2;
  }
  __syncthreads();
  const uint32_t* bb = base + (size_t)batch * 65536;
#pragma unroll
  for (int r = 0; r < 16; ++r) {
    uint32_t key = keyv[r];
    uint32_t d = (key >> shift) & 2047u;
    uint32_t pos = bb[d * 32 + blk] + whist[wv * 2048 + d] + posv[r];
    out[batchbase + pos] = key;
  }
}

// 8-bit pass (batch-0 only, bits 22..29): reuses classic layout on HIST[0..8192)
__global__ __launch_bounds__(256) void k_rh8(const uint32_t* __restrict__ in,
                                             uint32_t* __restrict__ hist, int shift) {
  __shared__ uint32_t h[256];
  int tid = threadIdx.x;
  int blk = blockIdx.x & 31;
  h[tid] = 0;
  __syncthreads();
  const uint32_t* keys = in + (size_t)blk * 4096;
  for (int r = 0; r < 16; ++r) {
    uint32_t d = (keys[r * 256 + tid] >> shift) & 255u;
    atomicAdd(&h[d], 1u);
  }
  __syncthreads();
  hist[(size_t)tid * 32 + blk] = h[tid];
}

__global__ __launch_bounds__(256) void k_rs8(const uint32_t* __restrict__ in,
                                             uint32_t* __restrict__ out,
                                             const uint32_t* __restrict__ base, int shift) {
  __shared__ uint32_t whist[4 * 256];
  int tid = threadIdx.x;
  int wv = tid >> 6, lane = tid & 63;
  int blk = blockIdx.x & 31;
  const uint32_t* src = in + (size_t)blk * 4096 + (size_t)wv * 1024;

  for (int i = tid; i < 4 * 256; i += 256) whist[i] = 0;
  __syncthreads();

  uint32_t keyv[16], posv[16];
#pragma unroll
  for (int r = 0; r < 16; ++r) {
    uint32_t key = src[r * 64 + lane];
    uint32_t d = (key >> shift) & 255u;
    unsigned long long m = match_mask<8>(d);
    unsigned long long below = m & ((1ull << lane) - 1ull);
    uint32_t rank = (uint32_t)__popcll(below);
    uint32_t cnt = (uint32_t)__popcll(m);
    uint32_t bse = whist[wv * 256 + d];
    if (below == 0ull) whist[wv * 256 + d] = bse + cnt;
    keyv[r] = key;
    posv[r] = bse + rank;
  }
  __syncthreads();
  {
    uint32_t a0 = whist[tid], a1 = whist[256 + tid], a2 = whist[512 + tid];
    whist[tid] = 0;
    whist[256 + tid] = a0;
    whist[512 + tid] = a0 + a1;
    whist[768 + tid] = a0 + a1 + a2;
  }
  __syncthreads();
#pragma unroll
  for (int r = 0; r < 16; ++r) {
    uint32_t key = keyv[r];
    uint32_t d = (key >> shift) & 255u;
    uint32_t pos = base[d * 32 + blk] + whist[wv * 256 + d] + posv[r];
    out[pos] = key;
  }
}

// ---------- level-1 quantiles (batch 0 sorted in sA; batches>=1 in sB) ----------

__global__ __launch_bounds__(64) void k_quantile1(const uint32_t* __restrict__ sA,
                                                  const uint32_t* __restrict__ sB,
                                                  float* __restrict__ qb1) {
#pragma clang fp contract(off)
  int batch = blockIdx.x, t = threadIdx.x;
  if (t >= 63) return;
  float qv = quant_frac(t);
  float q = qv * 131071.0f;
  int lo = (int)floorf(q);
  const uint32_t* s = (batch == 0 ? sA : sB) + (size_t)batch * NPTS;
  uint32_t u0 = __float_as_uint((float)(8 * batch));
  float vlo = __uint_as_float(s[lo] + u0);
  float vhi = __uint_as_float(s[lo + 1] + u0);
  qb1[batch * 64 + t] = jax_quantile_lerp(vlo, vhi, q);
}

// ---------- level-1 stable counting sort by bucket ----------

__global__ __launch_bounds__(256) void k_bhist(const float* __restrict__ coords,
                                               const float* __restrict__ qb1,
                                               uint32_t* __restrict__ hist) {
#pragma clang fp contract(off)
  __shared__ uint32_t h[64];
  __shared__ float qb[63];
  int tid = threadIdx.x;
  int batch = blockIdx.x >> 5, blk = blockIdx.x & 31;
  if (tid < 64) h[tid] = 0;
  if (tid >= 64 && tid < 127) qb[tid - 64] = qb1[batch * 64 + (tid - 64)];
  __syncthreads();
  const float* c = coords + (size_t)(batch * 2) * NPTS + (size_t)blk * 4096;
  float off = (float)(8 * batch);
  for (int r = 0; r < 16; ++r) {
    float v = c[r * 256 + tid] + off;
    uint32_t d = 0;
#pragma unroll
    for (int k = 0; k < 63; ++k) d += (qb[k] <= v) ? 1u : 0u;
    atomicAdd(&h[d], 1u);
  }
  __syncthreads();
  if (tid < 64) hist[((size_t)batch * 64 + tid) * 32 + blk] = h[tid];
}

__global__ __launch_bounds__(256) void k_bscatter(const float* __restrict__ coords,
                                                  const float* __restrict__ qb1,
                                                  const uint32_t* __restrict__ base,
                                                  int* __restrict__ idxout) {
#pragma clang fp contract(off)
  __shared__ uint32_t whist[4 * 64];
  __shared__ float qb[63];
  int tid = threadIdx.x;
  int wv = tid >> 6, lane = tid & 63;
  int batch = blockIdx.x >> 5, blk = blockIdx.x & 31;
  if (tid < 4 * 64) whist[tid] = 0;
  if (tid >= 192 && tid < 255) qb[tid - 192] = qb1[batch * 64 + (tid - 192)];
  __syncthreads();
  const float* c = coords + (size_t)(batch * 2) * NPTS + (size_t)blk * 4096 + (size_t)wv * 1024;
  float off = (float)(8 * batch);
  uint32_t bkv[16], rkv[16];
#pragma unroll
  for (int r = 0; r < 16; ++r) {
    float v = c[r * 64 + lane] + off;
    uint32_t d = 0;
#pragma unroll
    for (int k = 0; k < 63; ++k) d += (qb[k] <= v) ? 1u : 0u;
    unsigned long long m = match_mask<6>(d);
    unsigned long long below = m & ((1ull << lane) - 1ull);
    uint32_t rank = (uint32_t)__popcll(below);
    uint32_t cnt = (uint32_t)__popcll(m);
    uint32_t bse = whist[wv * 64 + d];
    if (below == 0ull) whist[wv * 64 + d] = bse + cnt;
    bkv[r] = d;
    rkv[r] = bse + rank;
  }
  __syncthreads();
  if (tid < 64) {
    uint32_t a0 = whist[tid], a1 = whist[64 + tid], a2 = whist[128 + tid];
    whist[tid] = 0;
    whist[64 + tid] = a0;
    whist[128 + tid] = a0 + a1;
    whist[192 + tid] = a0 + a1 + a2;
  }
  __syncthreads();
  const uint32_t* bb = base + (size_t)batch * 2048;
  int ibase = blk * 4096 + wv * 1024;
#pragma unroll
  for (int r = 0; r < 16; ++r) {
    uint32_t d = bkv[r];
    uint32_t pos = bb[d * 32 + blk] + whist[wv * 64 + d] + rkv[r];
    idxout[(size_t)batch * NPTS + pos] = ibase + r * 64 + lane;
  }
}

// ---------- level-2: adjusted-key radix (2 passes rows>=1) + bucket sort ----------

__global__ __launch_bounds__(256) void k_level2(const int* __restrict__ idx1,
                                                const float* __restrict__ coords,
                                                int* __restrict__ idxT,
                                                float* __restrict__ cm) {
#pragma clang fp contract(off)
  __shared__ int gidx[2048];
  __shared__ float ckey[2048];
  __shared__ uint32_t sbA[2048];
  __shared__ uint32_t sbB[2048];
  __shared__ uint32_t whist[4 * 256];
  __shared__ uint32_t base[256];
  __shared__ uint32_t wavetot[4];
  __shared__ float qb[63];

  const int tid = threadIdx.x;
  const int wv = tid >> 6, lane = tid & 63;
  const int row = blockIdx.x;
  const int b = row >> 6, i1 = row & 63;
  const float offf = (float)(512 * row);
  const uint32_t u0 = __float_as_uint(offf);

  for (int j = tid; j < 2048; j += 256) {
    int g = idx1[(size_t)b * NPTS + i1 * 2048 + j];
    gidx[j] = g;
    float cv = coords[((size_t)(b * 2 + 1)) * NPTS + g] + offf;
    ckey[j] = cv;
    sbA[j] = __float_as_uint(cv) - u0;
  }
  __syncthreads();

  const int npass = (row == 0) ? 4 : 2;
  uint32_t* A = sbA;
  uint32_t* B = sbB;
  for (int pass = 0; pass < npass; ++pass) {
    const int shift = pass * 8;
    for (int i = tid; i < 1024; i += 256) whist[i] = 0;
    __syncthreads();
    uint32_t keyv[8], posv[8];
#pragma unroll
    for (int r = 0; r < 8; ++r) {
      int j = wv * 512 + r * 64 + lane;
      uint32_t key = A[j];
      uint32_t d = (key >> shift) & 255u;
      unsigned long long m = match_mask<8>(d);
      unsigned long long below = m & ((1ull << lane) - 1ull);
      uint32_t rank = (uint32_t)__popcll(below);
      uint32_t cnt = (uint32_t)__popcll(m);
      uint32_t bse = whist[wv * 256 + d];
      if (below == 0ull) whist[wv * 256 + d] = bse + cnt;
      keyv[r] = key;
      posv[r] = bse + rank;
    }
    __syncthreads();
    {
      uint32_t a0 = whist[tid], a1 = whist[256 + tid], a2 = whist[512 + tid],
               a3 = whist[768 + tid];
      base[tid] = a0 + a1 + a2 + a3;
      whist[tid] = 0;
      whist[256 + tid] = a0;
      whist[512 + tid] = a0 + a1;
      whist[768 + tid] = a0 + a1 + a2;
    }
    __syncthreads();
    {
      uint32_t v = base[tid];
      uint32_t inc = v;
#pragma unroll
      for (int d2 = 1; d2 < 64; d2 <<= 1) {
        uint32_t u = __shfl_up(inc, d2, 64);
        if (lane >= d2) inc += u;
      }
      if (lane == 63) wavetot[wv] = inc;
      __syncthreads();
      uint32_t woff = 0;
      for (int w2 = 0; w2 < wv; ++w2) woff += wavetot[w2];
      base[tid] = inc - v + woff;
    }
    __syncthreads();
#pragma unroll
    for (int r = 0; r < 8; ++r) {
      uint32_t d = (keyv[r] >> shift) & 255u;
      B[base[d] + whist[wv * 256 + d] + posv[r]] = keyv[r];
    }
    __syncthreads();
    uint32_t* t = A;
    A = B;
    B = t;
  }

  if (tid < 63) {
    float qv = quant_frac(tid);
    float q = qv * 2047.0f;
    int lo = (int)floorf(q);
    float vlo = __uint_as_float(sbA[lo] + u0);
    float vhi = __uint_as_float(sbA[lo + 1] + u0);
    qb[tid] = jax_quantile_lerp(vlo, vhi, q);
  }
  for (int i = tid; i < 256; i += 256) whist[i] = 0;
  __syncthreads();

  uint32_t dv[8], pv[8];
#pragma unroll
  for (int r = 0; r < 8; ++r) {
    int j = wv * 512 + r * 64 + lane;
    float cv = ckey[j];
    uint32_t d = 0;
#pragma unroll
    for (int k = 0; k < 63; ++k) d += (qb[k] <= cv) ? 1u : 0u;
    unsigned long long m = match_mask<6>(d);
    unsigned long long below = m & ((1ull << lane) - 1ull);
    uint32_t rank = (uint32_t)__popcll(below);
    uint32_t cnt = (uint32_t)__popcll(m);
    uint32_t bse = whist[wv * 64 + d];
    if (below == 0ull) whist[wv * 64 + d] = bse + cnt;
    dv[r] = d;
    pv[r] = bse + rank;
  }
  __syncthreads();
  if (tid < 64) {
    uint32_t a0 = whist[tid], a1 = whist[64 + tid], a2 = whist[128 + tid],
             a3 = whist[192 + tid];
    base[tid] = a0 + a1 + a2 + a3;
    whist[tid] = 0;
    whist[64 + tid] = a0;
    whist[128 + tid] = a0 + a1;
    whist[192 + tid] = a0 + a1 + a2;
  }
  __syncthreads();
  if (wv == 0) {
    uint32_t v = base[lane];
    uint32_t inc = v;
#pragma unroll
    for (int d2 = 1; d2 < 64; d2 <<= 1) {
      uint32_t u = __shfl_up(inc, d2, 64);
      if (lane >= d2) inc += u;
    }
    base[lane] = inc - v;
  }
  __syncthreads();
#pragma unroll
  for (int r = 0; r < 8; ++r) {
    int j = wv * 512 + r * 64 + lane;
    uint32_t pos = base[dv[r]] + whist[wv * 64 + dv[r]] + pv[r];
    sbB[pos] = (uint32_t)j;
  }
  __syncthreads();

  for (int p = tid; p < 2048; p += 256)
    idxT[(size_t)b * NPTS + i1 * 2048 + p] = gidx[sbB[p]];

  if (tid < 128) {
    int i2 = tid >> 1, d = tid & 1;
    float v[32];
#pragma unroll
    for (int m2 = 0; m2 < 32; ++m2)
      v[m2] = coords[((size_t)(b * 2 + d)) * NPTS + gidx[sbB[i2 * 32 + m2]]];
#pragma unroll
    for (int r = 0; r < 32; ++r) {
#pragma unroll
      for (int i = (r & 1); i + 1 < 32; i += 2) {
        float a = v[i], c2 = v[i + 1];
        v[i] = fminf(a, c2);
        v[i + 1] = fmaxf(a, c2);
      }
    }
    cm[(((size_t)(b * 2 + d)) * 64 + i1) * 64 + i2] = v[15];
  }
}

// ---------- padded coord grid CP[b*2+d][66][66] ----------

__global__ __launch_bounds__(256) void k_cp2(const float* __restrict__ cm,
                                             float* __restrict__ cp) {
#pragma clang fp contract(off)
  __shared__ float cp0[66][66];
  __shared__ float cp1[66][66];
  const int b = blockIdx.x;
  const int tid = threadIdx.x;
  const float* m0 = cm + (size_t)(b * 2) * 4096;
  const float* m1 = cm + (size_t)(b * 2 + 1) * 4096;

  for (int i = tid; i < 4096; i += 256) {
    int i1 = i >> 6, i2 = i & 63;
    cp0[1 + i1][1 + i2] = m0[i];
    cp1[1 + i1][1 + i2] = m1[i];
  }
  __syncthreads();

  if (tid < 64) {
    int i2 = tid;
    float mn = m0[i2], mx = m0[i2];
    for (int i1 = 1; i1 < 64; ++i1) {
      float v = m0[i1 * 64 + i2];
      mn = fminf(mn, v);
      mx = fmaxf(mx, v);
    }
    cp0[0][1 + i2] = mn - 0.5f;
    cp0[65][1 + i2] = mx + 0.5f;
  } else if (tid < 128) {
    int i1 = tid - 64;
    float mn = m1[i1 * 64], mx = m1[i1 * 64];
    for (int i2 = 1; i2 < 64; ++i2) {
      float v = m1[i1 * 64 + i2];
      mn = fminf(mn, v);
      mx = fmaxf(mx, v);
    }
    cp1[1 + i1][0] = mn - 0.5f;
    cp1[1 + i1][65] = mx + 0.5f;
  }
  __syncthreads();

  if (tid < 66) {
    cp0[tid][0] = cp0[tid][1];
    cp0[tid][65] = cp0[tid][64];
  } else if (tid < 132) {
    int w = tid - 66;
    cp1[0][w] = cp1[1][w];
    cp1[65][w] = cp1[64][w];
  }
  __syncthreads();

  for (int e = tid; e < 4356; e += 256) {
    int h = e / 66, w = e % 66;
    cp[((size_t)(b * 2) * 66 + h) * 66 + w] = cp0[h][w];
    cp[((size_t)(b * 2 + 1) * 66 + h) * 66 + w] = cp1[h][w];
  }
}

// ---------- fused bilinear column + argmin0 per (b,w) ----------

__global__ __launch_bounds__(128) void k_selA(const float* __restrict__ cp,
                                              int* __restrict__ ind0t,
                                              float* __restrict__ c1sel) {
#pragma clang fp contract(off)
  __shared__ float col0[132], col1[132];
  const int bw = blockIdx.x;
  const int b = bw / 132, wp = bw % 132;
  const int tid = threadIdx.x;
  const float R = (float)(65.0 / 131.0);

  float posw = (float)wp * R;
  int j0 = (int)floorf(posw);
  if (j0 < 0) j0 = 0;
  if (j0 > 65) j0 = 65;
  int j1 = j0 + 1;
  if (j1 > 65) j1 = 65;
  float wu = posw - (float)j0;

  const float* p0 = cp + (size_t)(b * 2) * 4356;
  const float* p1 = cp + (size_t)(b * 2 + 1) * 4356;

  for (int hp = tid; hp < 132; hp += 128) {
    float posh = (float)hp * R;
    int r0 = (int)floorf(posh);
    if (r0 < 0) r0 = 0;
    if (r0 > 65) r0 = 65;
    int r1 = r0 + 1;
    if (r1 > 65) r1 = 65;
    float wt = posh - (float)r0;
    float ta0 = bilerp1(p0[r0 * 66 + j0], p0[r1 * 66 + j0], wt);
    float tb0 = bilerp1(p0[r0 * 66 + j1], p0[r1 * 66 + j1], wt);
    float ta1 = bilerp1(p1[r0 * 66 + j0], p1[r1 * 66 + j0], wt);
    float tb1 = bilerp1(p1[r0 * 66 + j1], p1[r1 * 66 + j1], wt);
    col0[hp] = bilerp1(ta0, tb0, wu);
    col1[hp] = bilerp1(ta1, tb1, wu);
  }
  __syncthreads();
  if (tid < 64) {
    float gv = grid_val(tid);
    float best = fabsf(col0[0] - gv);
    int bi = 0;
    for (int h = 1; h < 132; ++h) {
      float d2 = fabsf(col0[h] - gv);
      if (d2 < best) { best = d2; bi = h; }
    }
    ind0t[((size_t)b * 64 + tid) * 132 + wp] = bi;
    c1sel[((size_t)b * 64 + tid) * 132 + wp] = col1[bi];
  }
}

__global__ __launch_bounds__(64) void k_sel1b(const float* __restrict__ c1sel,
                                              int* __restrict__ ind) {
#pragma clang fp contract(off)
  __shared__ float rv[132];
  int b = blockIdx.x >> 6, g0 = blockIdx.x & 63;
  int tid = threadIdx.x;
  for (int w = tid; w < 132; w += 64) rv[w] = c1sel[((size_t)b * 64 + g0) * 132 + w];
  __syncthreads();
  float gv = grid_val(tid);
  float best = fabsf(rv[0] - gv);
  int bi = 0;
  for (int w = 1; w < 132; ++w) {
    float d2 = fabsf(rv[w] - gv);
    if (d2 < best) { best = d2; bi = w; }
  }
  ind[((size_t)b * 64 + g0) * 64 + tid] = bi;
}

// ---------- gather x into cell-contiguous DB[b*4096+cell][256] ----------

__global__ __launch_bounds__(256) void k_db(const float* __restrict__ x,
                                            const int* __restrict__ idxT,
                                            float* __restrict__ db) {
  int t = blockIdx.x * 256 + threadIdx.x;
  int mi = t & 31;
  int cellLocal = (t >> 5) & 4095;
  int b = t >> 17;
  int g = idxT[(size_t)b * NPTS + cellLocal * 32 + mi];
  const float* src = x + ((size_t)b * NPTS + g) * 8;
  float4 lo = *(const float4*)(src);
  float4 hi = *(const float4*)(src + 4);
  float* dst = db + (size_t)t * 8;
  *(float4*)(dst) = lo;
  *(float4*)(dst + 4) = hi;
}

// ---------- final bicubic: lanes=channels, LDS transpose ----------

__global__ __launch_bounds__(256) void k_final3(const float* __restrict__ db,
                                                const int* __restrict__ ind,
                                                const int* __restrict__ ind0t,
                                                float* __restrict__ outp) {
#pragma clang fp contract(off)
  __shared__ int sRI[256], sCI[256];
  __shared__ float sWH[256], sWW[256];
  __shared__ float tile[64][65];

  const int bid = blockIdx.x;
  const int b = bid >> 8;
  const int p = (bid >> 2) & 63;
  const int cg = bid & 3;
  const int tid = threadIdx.x;
  const float R = (float)(65.0 / 131.0);

  if (tid < 64) {
    int qt = tid;
    int wstar = ind[((size_t)b * 64 + qt) * 64 + p];
    int hstar = ind0t[((size_t)b * 64 + qt) * 132 + wstar];
    float posh = (float)hstar * R;
    int i0h = (int)floorf(posh);
    float frh = posh - (float)i0h;
    float posw = (float)wstar * R;
    int i0w = (int)floorf(posw);
    float frw = posw - (float)i0w;
#pragma unroll
    for (int k = 0; k < 4; ++k) {
      int I = i0h + k - 1;
      I = I < 0 ? 0 : (I > 65 ? 65 : I);
      int rI = I - 1;
      sRI[qt * 4 + k] = rI < 0 ? 0 : (rI > 63 ? 63 : rI);
      sWH[qt * 4 + k] = cubw(frh - (float)(k - 1));
      int J = i0w + k - 1;
      J = J < 0 ? 0 : (J > 65 ? 65 : J);
      int cJ = J - 1;
      sCI[qt * 4 + k] = cJ < 0 ? 0 : (cJ > 63 ? 63 : cJ);
      sWW[qt * 4 + k] = cubw(frw - (float)(k - 1));
    }
  }
  __syncthreads();

  const int wave = tid >> 6, lane = tid & 63;
  const int ch = cg * 64 + lane;
  const size_t dbb = (size_t)(b * 4096) * 256 + ch;

  for (int s = 0; s < 16; ++s) {
    int qt = wave * 16 + s;
    float a = 0.0f;
#pragma unroll
    for (int l = 0; l < 4; ++l) {
      float t = 0.0f;
#pragma unroll
      for (int k = 0; k < 4; ++k) {
        float v = db[dbb + (size_t)(sRI[qt * 4 + k] * 64 + sCI[qt * 4 + l]) * 256];
        t = fmaf(v, sWH[qt * 4 + k], t);
      }
      a = fmaf(t, sWW[qt * 4 + l], a);
    }
    tile[qt][lane] = a;
  }
  __syncthreads();

  for (int it = 0; it < 16; ++it) {
    int qt2 = tid & 63;
    int cc = (tid >> 6) * 16 + it;
    outp[(((size_t)b * 256 + cg * 64 + cc) * 64 + p) * 64 + qt2] = tile[qt2][cc];
  }
}

// ---------- launch ----------

extern "C" void kernel_launch(void* const* d_in, const int* in_sizes, int n_in,
                              void* d_out, int out_size, void* d_ws, size_t ws_size,
                              hipStream_t stream) {
  (void)n_in; (void)out_size; (void)ws_size;
  const float* x;
  const float* coords;
  if (in_sizes[0] == 8388608) {
    x = (const float*)d_in[0];
    coords = (const float*)d_in[1];
  } else {
    coords = (const float*)d_in[0];
    x = (const float*)d_in[1];
  }
  float* outp = (float*)d_out;
  char* ws = (char*)d_ws;

  uint32_t* KA = (uint32_t*)(ws + 0);          // 4 MB
  uint32_t* KB = (uint32_t*)(ws + 4194304);    // 4 MB
  uint32_t* HIST = (uint32_t*)(ws + 8388608);  // 2 MB (8 x 2048 x 32)
  int* IDX1 = (int*)(ws + 10485760);           // 4 MB -> ends 14680064
  float* CP = (float*)(ws + 0);                // 278784 B (after radix dead)
  float* DB = (float*)(ws + 0);                // 33.5 MB (after CP consumed)

  size_t P = 33554432;
  int* IDXT = (int*)(ws + P);          P += 4194304;
  float* CM = (float*)(ws + P);        P += 262144;
  int* IND0T = (int*)(ws + P);         P += 270336;
  float* C1SEL = (float*)(ws + P);     P += 270336;
  int* IND = (int*)(ws + P);           P += 131072;
  float* QB1 = (float*)(ws + P);       P += 2048;

  // P0 (11-bit, bits 0-10, fused key calc): coords -> KA
  k_rh11_0<<<256, 256, 0, stream>>>(coords, HIST);
  k_scan<<<8, 256, 0, stream>>>(HIST, 65536);
  k_rs11_0<<<256, 256, 0, stream>>>(coords, KA, HIST);
  // P1 (11-bit, bits 11-21): KA -> KB
  k_rh11<<<256, 256, 0, stream>>>(KA, HIST, 11);
  k_scan<<<8, 256, 0, stream>>>(HIST, 65536);
  k_rs11<<<256, 256, 0, stream>>>(KA, KB, HIST, 11);
  // P2 (8-bit, bits 22-29, batch 0 only): KB -> KA
  k_rh8<<<32, 256, 0, stream>>>(KB, HIST, 22);
  k_scan<<<1, 256, 0, stream>>>(HIST, 8192);
  k_rs8<<<32, 256, 0, stream>>>(KB, KA, HIST, 22);
  // batch 0 sorted in KA; batches >=1 sorted in KB
  k_quantile1<<<8, 64, 0, stream>>>(KA, KB, QB1);

  k_bhist<<<256, 256, 0, stream>>>(coords, QB1, HIST);
  k_scan<<<8, 256, 0, stream>>>(HIST, 2048);
  k_bscatter<<<256, 256, 0, stream>>>(coords, QB1, HIST, IDX1);

  k_level2<<<512, 256, 0, stream>>>(IDX1, coords, IDXT, CM);

  k_cp2<<<8, 256, 0, stream>>>(CM, CP);
  k_selA<<<1056, 128, 0, stream>>>(CP, IND0T, C1SEL);
  k_sel1b<<<512, 64, 0, stream>>>(C1SEL, IND);

  k_db<<<4096, 256, 0, stream>>>(x, IDXT, DB);
  k_final3<<<2048, 256, 0, stream>>>(DB, IND, IND0T, outp);
}

// Round 17
// 233.839 us; speedup vs baseline: 1.8785x; 1.8785x over previous
//
#include <hip/hip_runtime.h>
#include <stdint.h>

#define NPTS 131072

// ---------- helpers (XLA:GPU contraction semantics: fma-fused) ----------

__device__ __forceinline__ float cubw(float t) {
#pragma clang fp contract(off)
  float at = fabsf(t);
  if (at <= 1.0f) {
    float u = fmaf(1.25f, at, -2.25f);
    u = u * at;
    return fmaf(u, at, 1.0f);
  } else if (at < 2.0f) {
    float u = at - 5.0f;
    u = fmaf(u, at, 8.0f);
    u = fmaf(u, at, -4.0f);
    return u * -0.75f;
  }
  return 0.0f;
}

__device__ __forceinline__ float quant_frac(int t) {
#pragma clang fp contract(off)
  return (float)(t + 1) * 0.015625f;
}

__device__ __forceinline__ float grid_val(int i) {
#pragma clang fp contract(off)
  return (float)i * (1.0f / 63.0f);
}

__device__ __forceinline__ float jax_quantile_lerp(float vlo, float vhi, float q) {
#pragma clang fp contract(off)
  float lowf = floorf(q);
  float highf = ceilf(q);
  float hw = q - lowf;
  float lw = highf - q;
  float bh = vhi * hw;
  return fmaf(vlo, lw, bh);
}

__device__ __forceinline__ float bilerp1(float a, float b, float w) {
#pragma clang fp contract(off)
  float omw = 1.0f - w;
  float bw = b * w;
  return fmaf(a, omw, bw);
}

template <int NB>
__device__ __forceinline__ unsigned long long match_mask(uint32_t d) {
  unsigned long long m = ~0ull;
#pragma unroll
  for (int i = 0; i < NB; ++i) {
    unsigned long long bal = __ballot((int)((d >> i) & 1u));
    m &= ((d >> i) & 1u) ? bal : ~bal;
  }
  return m;
}

// adjusted level-1 key: u(fl(x + 8b)) - u(8b)  (order-preserving)
__device__ __forceinline__ uint32_t l1key(const float* coords, int batch, int idx) {
#pragma clang fp contract(off)
  float off = (float)(8 * batch);
  float c = coords[(size_t)(batch * 2) * NPTS + idx] + off;
  return __float_as_uint(c) - __float_as_uint(off);
}

// ---------- parallel exclusive scan over [bins][32] per batch ----------

__global__ __launch_bounds__(256) void k_scan2(uint32_t* __restrict__ buf, int bins) {
  __shared__ uint32_t lds[256 * 33];
  __shared__ uint32_t wavetot[4];
  const int batch = blockIdx.x, tid = threadIdx.x;
  const int lane = tid & 63, wv = tid >> 6;
  uint32_t* p = buf + (size_t)batch * bins * 32;
  const int n = bins * 32;
  for (int i = tid; i < n; i += 256) {
    int d = i >> 5, blk = i & 31;
    lds[d * 33 + blk] = p[i];
  }
  __syncthreads();
  uint32_t mysum = 0;
  if (tid < bins) {
#pragma unroll 8
    for (int blk = 0; blk < 32; ++blk) mysum += lds[tid * 33 + blk];
  }
  uint32_t inc = mysum;
#pragma unroll
  for (int d2 = 1; d2 < 64; d2 <<= 1) {
    uint32_t u = __shfl_up(inc, d2, 64);
    if (lane >= d2) inc += u;
  }
  if (lane == 63) wavetot[wv] = inc;
  __syncthreads();
  uint32_t woff = 0;
  for (int w2 = 0; w2 < wv; ++w2) woff += wavetot[w2];
  uint32_t binbase = inc - mysum + woff;
  if (tid < bins) {
    uint32_t run = binbase;
#pragma unroll 8
    for (int blk = 0; blk < 32; ++blk) {
      uint32_t t = lds[tid * 33 + blk];
      p[tid * 32 + blk] = run;
      run += t;
    }
  }
}

// ---------- LSD radix (8-bit): generic hist/scatter on materialized keys ----------

__global__ __launch_bounds__(256) void k_radix_hist(const uint32_t* __restrict__ in,
                                                    uint32_t* __restrict__ hist, int shift,
                                                    int batch0) {
  __shared__ uint32_t h[256];
  int tid = threadIdx.x;
  int batch = (blockIdx.x >> 5) + batch0, blk = blockIdx.x & 31;
  h[tid] = 0;
  __syncthreads();
  const uint32_t* keys = in + (size_t)batch * NPTS + (size_t)blk * 4096;
  for (int r = 0; r < 16; ++r) {
    uint32_t d = (keys[r * 256 + tid] >> shift) & 255u;
    atomicAdd(&h[d], 1u);
  }
  __syncthreads();
  hist[((size_t)batch * 256 + tid) * 32 + blk] = h[tid];
}

__global__ __launch_bounds__(256) void k_radix_scatter(const uint32_t* __restrict__ in,
                                                       uint32_t* __restrict__ out,
                                                       const uint32_t* __restrict__ base,
                                                       int shift, int batch0) {
  __shared__ uint32_t whist[4 * 256];
  int tid = threadIdx.x;
  int wv = tid >> 6, lane = tid & 63;
  int batch = (blockIdx.x >> 5) + batch0, blk = blockIdx.x & 31;
  size_t batchbase = (size_t)batch * NPTS;
  const uint32_t* src = in + batchbase + (size_t)blk * 4096 + (size_t)wv * 1024;

  for (int i = tid; i < 4 * 256; i += 256) whist[i] = 0;
  __syncthreads();

  uint32_t keyv[16], posv[16];
#pragma unroll
  for (int r = 0; r < 16; ++r) {
    uint32_t key = src[r * 64 + lane];
    uint32_t d = (key >> shift) & 255u;
    unsigned long long m = match_mask<8>(d);
    unsigned long long below = m & ((1ull << lane) - 1ull);
    uint32_t rank = (uint32_t)__popcll(below);
    uint32_t cnt = (uint32_t)__popcll(m);
    uint32_t bse = whist[wv * 256 + d];
    if (below == 0ull) whist[wv * 256 + d] = bse + cnt;
    keyv[r] = key;
    posv[r] = bse + rank;
  }
  __syncthreads();
  {
    uint32_t a0 = whist[tid], a1 = whist[256 + tid], a2 = whist[512 + tid];
    whist[tid] = 0;
    whist[256 + tid] = a0;
    whist[512 + tid] = a0 + a1;
    whist[768 + tid] = a0 + a1 + a2;
  }
  __syncthreads();
  const uint32_t* bb = base + (size_t)batch * 8192;
#pragma unroll
  for (int r = 0; r < 16; ++r) {
    uint32_t key = keyv[r];
    uint32_t d = (key >> shift) & 255u;
    uint32_t pos = bb[d * 32 + blk] + whist[wv * 256 + d] + posv[r];
    out[batchbase + pos] = key;
  }
}

// pass-0 variants: compute adjusted key from coords inline

__global__ __launch_bounds__(256) void k_radix_hist0(const float* __restrict__ coords,
                                                     uint32_t* __restrict__ hist) {
  __shared__ uint32_t h[256];
  int tid = threadIdx.x;
  int batch = blockIdx.x >> 5, blk = blockIdx.x & 31;
  h[tid] = 0;
  __syncthreads();
  for (int r = 0; r < 16; ++r) {
    uint32_t d = l1key(coords, batch, blk * 4096 + r * 256 + tid) & 255u;
    atomicAdd(&h[d], 1u);
  }
  __syncthreads();
  hist[((size_t)batch * 256 + tid) * 32 + blk] = h[tid];
}

__global__ __launch_bounds__(256) void k_radix_scatter0(const float* __restrict__ coords,
                                                        uint32_t* __restrict__ out,
                                                        const uint32_t* __restrict__ base) {
  __shared__ uint32_t whist[4 * 256];
  int tid = threadIdx.x;
  int wv = tid >> 6, lane = tid & 63;
  int batch = blockIdx.x >> 5, blk = blockIdx.x & 31;
  size_t batchbase = (size_t)batch * NPTS;

  for (int i = tid; i < 4 * 256; i += 256) whist[i] = 0;
  __syncthreads();

  uint32_t keyv[16], posv[16];
#pragma unroll
  for (int r = 0; r < 16; ++r) {
    uint32_t key = l1key(coords, batch, blk * 4096 + wv * 1024 + r * 64 + lane);
    uint32_t d = key & 255u;
    unsigned long long m = match_mask<8>(d);
    unsigned long long below = m & ((1ull << lane) - 1ull);
    uint32_t rank = (uint32_t)__popcll(below);
    uint32_t cnt = (uint32_t)__popcll(m);
    uint32_t bse = whist[wv * 256 + d];
    if (below == 0ull) whist[wv * 256 + d] = bse + cnt;
    keyv[r] = key;
    posv[r] = bse + rank;
  }
  __syncthreads();
  {
    uint32_t a0 = whist[tid], a1 = whist[256 + tid], a2 = whist[512 + tid];
    whist[tid] = 0;
    whist[256 + tid] = a0;
    whist[512 + tid] = a0 + a1;
    whist[768 + tid] = a0 + a1 + a2;
  }
  __syncthreads();
  const uint32_t* bb = base + (size_t)batch * 8192;
#pragma unroll
  for (int r = 0; r < 16; ++r) {
    uint32_t key = keyv[r];
    uint32_t d = key & 255u;
    uint32_t pos = bb[d * 32 + blk] + whist[wv * 256 + d] + posv[r];
    out[batchbase + pos] = key;
  }
}

// ---------- level-1 quantiles (batch 0 sorted in sA; batches>=1 in sB) ----------

__global__ __launch_bounds__(64) void k_quantile1(const uint32_t* __restrict__ sA,
                                                  const uint32_t* __restrict__ sB,
                                                  float* __restrict__ qb1) {
#pragma clang fp contract(off)
  int batch = blockIdx.x, t = threadIdx.x;
  if (t >= 63) return;
  float qv = quant_frac(t);
  float q = qv * 131071.0f;
  int lo = (int)floorf(q);
  const uint32_t* s = (batch == 0 ? sA : sB) + (size_t)batch * NPTS;
  uint32_t u0 = __float_as_uint((float)(8 * batch));
  float vlo = __uint_as_float(s[lo] + u0);
  float vhi = __uint_as_float(s[lo + 1] + u0);
  qb1[batch * 64 + t] = jax_quantile_lerp(vlo, vhi, q);
}

// ---------- level-1 stable counting sort by bucket ----------

__global__ __launch_bounds__(256) void k_bhist(const float* __restrict__ coords,
                                               const float* __restrict__ qb1,
                                               uint32_t* __restrict__ hist) {
#pragma clang fp contract(off)
  __shared__ uint32_t h[64];
  __shared__ float qb[63];
  int tid = threadIdx.x;
  int batch = blockIdx.x >> 5, blk = blockIdx.x & 31;
  if (tid < 64) h[tid] = 0;
  if (tid >= 64 && tid < 127) qb[tid - 64] = qb1[batch * 64 + (tid - 64)];
  __syncthreads();
  const float* c = coords + (size_t)(batch * 2) * NPTS + (size_t)blk * 4096;
  float off = (float)(8 * batch);
  for (int r = 0; r < 16; ++r) {
    float v = c[r * 256 + tid] + off;
    uint32_t d = 0;
#pragma unroll
    for (int k = 0; k < 63; ++k) d += (qb[k] <= v) ? 1u : 0u;
    atomicAdd(&h[d], 1u);
  }
  __syncthreads();
  if (tid < 64) hist[((size_t)batch * 64 + tid) * 32 + blk] = h[tid];
}

__global__ __launch_bounds__(256) void k_bscatter(const float* __restrict__ coords,
                                                  const float* __restrict__ qb1,
                                                  const uint32_t* __restrict__ base,
                                                  int* __restrict__ idxout) {
#pragma clang fp contract(off)
  __shared__ uint32_t whist[4 * 64];
  __shared__ float qb[63];
  int tid = threadIdx.x;
  int wv = tid >> 6, lane = tid & 63;
  int batch = blockIdx.x >> 5, blk = blockIdx.x & 31;
  if (tid < 4 * 64) whist[tid] = 0;
  if (tid >= 192 && tid < 255) qb[tid - 192] = qb1[batch * 64 + (tid - 192)];
  __syncthreads();
  const float* c = coords + (size_t)(batch * 2) * NPTS + (size_t)blk * 4096 + (size_t)wv * 1024;
  float off = (float)(8 * batch);
  uint32_t bkv[16], rkv[16];
#pragma unroll
  for (int r = 0; r < 16; ++r) {
    float v = c[r * 64 + lane] + off;
    uint32_t d = 0;
#pragma unroll
    for (int k = 0; k < 63; ++k) d += (qb[k] <= v) ? 1u : 0u;
    unsigned long long m = match_mask<6>(d);
    unsigned long long below = m & ((1ull << lane) - 1ull);
    uint32_t rank = (uint32_t)__popcll(below);
    uint32_t cnt = (uint32_t)__popcll(m);
    uint32_t bse = whist[wv * 64 + d];
    if (below == 0ull) whist[wv * 64 + d] = bse + cnt;
    bkv[r] = d;
    rkv[r] = bse + rank;
  }
  __syncthreads();
  if (tid < 64) {
    uint32_t a0 = whist[tid], a1 = whist[64 + tid], a2 = whist[128 + tid];
    whist[tid] = 0;
    whist[64 + tid] = a0;
    whist[128 + tid] = a0 + a1;
    whist[192 + tid] = a0 + a1 + a2;
  }
  __syncthreads();
  const uint32_t* bb = base + (size_t)batch * 2048;
  int ibase = blk * 4096 + wv * 1024;
#pragma unroll
  for (int r = 0; r < 16; ++r) {
    uint32_t d = bkv[r];
    uint32_t pos = bb[d * 32 + blk] + whist[wv * 64 + d] + rkv[r];
    idxout[(size_t)batch * NPTS + pos] = ibase + r * 64 + lane;
  }
}

// ---------- level-2: adjusted-key radix (2 passes rows>=1) + bucket sort ----------

__global__ __launch_bounds__(256) void k_level2(const int* __restrict__ idx1,
                                                const float* __restrict__ coords,
                                                int* __restrict__ idxT,
                                                float* __restrict__ cm) {
#pragma clang fp contract(off)
  __shared__ int gidx[2048];
  __shared__ float ckey[2048];
  __shared__ uint32_t sbA[2048];
  __shared__ uint32_t sbB[2048];
  __shared__ uint32_t whist[4 * 256];
  __shared__ uint32_t base[256];
  __shared__ uint32_t wavetot[4];
  __shared__ float qb[63];

  const int tid = threadIdx.x;
  const int wv = tid >> 6, lane = tid & 63;
  const int row = blockIdx.x;
  const int b = row >> 6, i1 = row & 63;
  const float offf = (float)(512 * row);
  const uint32_t u0 = __float_as_uint(offf);

  for (int j = tid; j < 2048; j += 256) {
    int g = idx1[(size_t)b * NPTS + i1 * 2048 + j];
    gidx[j] = g;
    float cv = coords[((size_t)(b * 2 + 1)) * NPTS + g] + offf;
    ckey[j] = cv;
    sbA[j] = __float_as_uint(cv) - u0;
  }
  __syncthreads();

  const int npass = (row == 0) ? 4 : 2;
  uint32_t* A = sbA;
  uint32_t* B = sbB;
  for (int pass = 0; pass < npass; ++pass) {
    const int shift = pass * 8;
    for (int i = tid; i < 1024; i += 256) whist[i] = 0;
    __syncthreads();
    uint32_t keyv[8], posv[8];
#pragma unroll
    for (int r = 0; r < 8; ++r) {
      int j = wv * 512 + r * 64 + lane;
      uint32_t key = A[j];
      uint32_t d = (key >> shift) & 255u;
      unsigned long long m = match_mask<8>(d);
      unsigned long long below = m & ((1ull << lane) - 1ull);
      uint32_t rank = (uint32_t)__popcll(below);
      uint32_t cnt = (uint32_t)__popcll(m);
      uint32_t bse = whist[wv * 256 + d];
      if (below == 0ull) whist[wv * 256 + d] = bse + cnt;
      keyv[r] = key;
      posv[r] = bse + rank;
    }
    __syncthreads();
    {
      uint32_t a0 = whist[tid], a1 = whist[256 + tid], a2 = whist[512 + tid],
               a3 = whist[768 + tid];
      base[tid] = a0 + a1 + a2 + a3;
      whist[tid] = 0;
      whist[256 + tid] = a0;
      whist[512 + tid] = a0 + a1;
      whist[768 + tid] = a0 + a1 + a2;
    }
    __syncthreads();
    {
      uint32_t v = base[tid];
      uint32_t inc = v;
#pragma unroll
      for (int d2 = 1; d2 < 64; d2 <<= 1) {
        uint32_t u = __shfl_up(inc, d2, 64);
        if (lane >= d2) inc += u;
      }
      if (lane == 63) wavetot[wv] = inc;
      __syncthreads();
      uint32_t woff = 0;
      for (int w2 = 0; w2 < wv; ++w2) woff += wavetot[w2];
      base[tid] = inc - v + woff;
    }
    __syncthreads();
#pragma unroll
    for (int r = 0; r < 8; ++r) {
      uint32_t d = (keyv[r] >> shift) & 255u;
      B[base[d] + whist[wv * 256 + d] + posv[r]] = keyv[r];
    }
    __syncthreads();
    uint32_t* t = A;
    A = B;
    B = t;
  }

  if (tid < 63) {
    float qv = quant_frac(tid);
    float q = qv * 2047.0f;
    int lo = (int)floorf(q);
    float vlo = __uint_as_float(sbA[lo] + u0);
    float vhi = __uint_as_float(sbA[lo + 1] + u0);
    qb[tid] = jax_quantile_lerp(vlo, vhi, q);
  }
  for (int i = tid; i < 256; i += 256) whist[i] = 0;
  __syncthreads();

  uint32_t dv[8], pv[8];
#pragma unroll
  for (int r = 0; r < 8; ++r) {
    int j = wv * 512 + r * 64 + lane;
    float cv = ckey[j];
    uint32_t d = 0;
#pragma unroll
    for (int k = 0; k < 63; ++k) d += (qb[k] <= cv) ? 1u : 0u;
    unsigned long long m = match_mask<6>(d);
    unsigned long long below = m & ((1ull << lane) - 1ull);
    uint32_t rank = (uint32_t)__popcll(below);
    uint32_t cnt = (uint32_t)__popcll(m);
    uint32_t bse = whist[wv * 64 + d];
    if (below == 0ull) whist[wv * 64 + d] = bse + cnt;
    dv[r] = d;
    pv[r] = bse + rank;
  }
  __syncthreads();
  if (tid < 64) {
    uint32_t a0 = whist[tid], a1 = whist[64 + tid], a2 = whist[128 + tid],
             a3 = whist[192 + tid];
    base[tid] = a0 + a1 + a2 + a3;
    whist[tid] = 0;
    whist[64 + tid] = a0;
    whist[128 + tid] = a0 + a1;
    whist[192 + tid] = a0 + a1 + a2;
  }
  __syncthreads();
  if (wv == 0) {
    uint32_t v = base[lane];
    uint32_t inc = v;
#pragma unroll
    for (int d2 = 1; d2 < 64; d2 <<= 1) {
      uint32_t u = __shfl_up(inc, d2, 64);
      if (lane >= d2) inc += u;
    }
    base[lane] = inc - v;
  }
  __syncthreads();
#pragma unroll
  for (int r = 0; r < 8; ++r) {
    int j = wv * 512 + r * 64 + lane;
    uint32_t pos = base[dv[r]] + whist[wv * 64 + dv[r]] + pv[r];
    sbB[pos] = (uint32_t)j;
  }
  __syncthreads();

  for (int p = tid; p < 2048; p += 256)
    idxT[(size_t)b * NPTS + i1 * 2048 + p] = gidx[sbB[p]];

  if (tid < 128) {
    int i2 = tid >> 1, d = tid & 1;
    float v[32];
#pragma unroll
    for (int m2 = 0; m2 < 32; ++m2)
      v[m2] = coords[((size_t)(b * 2 + d)) * NPTS + gidx[sbB[i2 * 32 + m2]]];
#pragma unroll
    for (int r = 0; r < 32; ++r) {
#pragma unroll
      for (int i = (r & 1); i + 1 < 32; i += 2) {
        float a = v[i], c2 = v[i + 1];
        v[i] = fminf(a, c2);
        v[i + 1] = fmaxf(a, c2);
      }
    }
    cm[(((size_t)(b * 2 + d)) * 64 + i1) * 64 + i2] = v[15];
  }
}

// ---------- padded coord grid CP[b*2+d][66][66] ----------

__global__ __launch_bounds__(256) void k_cp2(const float* __restrict__ cm,
                                             float* __restrict__ cp) {
#pragma clang fp contract(off)
  __shared__ float cp0[66][66];
  __shared__ float cp1[66][66];
  const int b = blockIdx.x;
  const int tid = threadIdx.x;
  const float* m0 = cm + (size_t)(b * 2) * 4096;
  const float* m1 = cm + (size_t)(b * 2 + 1) * 4096;

  for (int i = tid; i < 4096; i += 256) {
    int i1 = i >> 6, i2 = i & 63;
    cp0[1 + i1][1 + i2] = m0[i];
    cp1[1 + i1][1 + i2] = m1[i];
  }
  __syncthreads();

  if (tid < 64) {
    int i2 = tid;
    float mn = m0[i2], mx = m0[i2];
    for (int i1 = 1; i1 < 64; ++i1) {
      float v = m0[i1 * 64 + i2];
      mn = fminf(mn, v);
      mx = fmaxf(mx, v);
    }
    cp0[0][1 + i2] = mn - 0.5f;
    cp0[65][1 + i2] = mx + 0.5f;
  } else if (tid < 128) {
    int i1 = tid - 64;
    float mn = m1[i1 * 64], mx = m1[i1 * 64];
    for (int i2 = 1; i2 < 64; ++i2) {
      float v = m1[i1 * 64 + i2];
      mn = fminf(mn, v);
      mx = fmaxf(mx, v);
    }
    cp1[1 + i1][0] = mn - 0.5f;
    cp1[1 + i1][65] = mx + 0.5f;
  }
  __syncthreads();

  if (tid < 66) {
    cp0[tid][0] = cp0[tid][1];
    cp0[tid][65] = cp0[tid][64];
  } else if (tid < 132) {
    int w = tid - 66;
    cp1[0][w] = cp1[1][w];
    cp1[65][w] = cp1[64][w];
  }
  __syncthreads();

  for (int e = tid; e < 4356; e += 256) {
    int h = e / 66, w = e % 66;
    cp[((size_t)(b * 2) * 66 + h) * 66 + w] = cp0[h][w];
    cp[((size_t)(b * 2 + 1) * 66 + h) * 66 + w] = cp1[h][w];
  }
}

// ---------- fused bilinear column + argmin0 per (b,w) ----------

__global__ __launch_bounds__(128) void k_selA(const float* __restrict__ cp,
                                              int* __restrict__ ind0t,
                                              float* __restrict__ c1sel) {
#pragma clang fp contract(off)
  __shared__ float col0[132], col1[132];
  const int bw = blockIdx.x;
  const int b = bw / 132, wp = bw % 132;
  const int tid = threadIdx.x;
  const float R = (float)(65.0 / 131.0);

  float posw = (float)wp * R;
  int j0 = (int)floorf(posw);
  if (j0 < 0) j0 = 0;
  if (j0 > 65) j0 = 65;
  int j1 = j0 + 1;
  if (j1 > 65) j1 = 65;
  float wu = posw - (float)j0;

  const float* p0 = cp + (size_t)(b * 2) * 4356;
  const float* p1 = cp + (size_t)(b * 2 + 1) * 4356;

  for (int hp = tid; hp < 132; hp += 128) {
    float posh = (float)hp * R;
    int r0 = (int)floorf(posh);
    if (r0 < 0) r0 = 0;
    if (r0 > 65) r0 = 65;
    int r1 = r0 + 1;
    if (r1 > 65) r1 = 65;
    float wt = posh - (float)r0;
    float ta0 = bilerp1(p0[r0 * 66 + j0], p0[r1 * 66 + j0], wt);
    float tb0 = bilerp1(p0[r0 * 66 + j1], p0[r1 * 66 + j1], wt);
    float ta1 = bilerp1(p1[r0 * 66 + j0], p1[r1 * 66 + j0], wt);
    float tb1 = bilerp1(p1[r0 * 66 + j1], p1[r1 * 66 + j1], wt);
    col0[hp] = bilerp1(ta0, tb0, wu);
    col1[hp] = bilerp1(ta1, tb1, wu);
  }
  __syncthreads();
  if (tid < 64) {
    float gv = grid_val(tid);
    float best = fabsf(col0[0] - gv);
    int bi = 0;
    for (int h = 1; h < 132; ++h) {
      float d2 = fabsf(col0[h] - gv);
      if (d2 < best) { best = d2; bi = h; }
    }
    ind0t[((size_t)b * 64 + tid) * 132 + wp] = bi;
    c1sel[((size_t)b * 64 + tid) * 132 + wp] = col1[bi];
  }
}

__global__ __launch_bounds__(64) void k_sel1b(const float* __restrict__ c1sel,
                                              int* __restrict__ ind) {
#pragma clang fp contract(off)
  __shared__ float rv[132];
  int b = blockIdx.x >> 6, g0 = blockIdx.x & 63;
  int tid = threadIdx.x;
  for (int w = tid; w < 132; w += 64) rv[w] = c1sel[((size_t)b * 64 + g0) * 132 + w];
  __syncthreads();
  float gv = grid_val(tid);
  float best = fabsf(rv[0] - gv);
  int bi = 0;
  for (int w = 1; w < 132; ++w) {
    float d2 = fabsf(rv[w] - gv);
    if (d2 < best) { best = d2; bi = w; }
  }
  ind[((size_t)b * 64 + g0) * 64 + tid] = bi;
}

// ---------- gather x into cell-contiguous DB[b*4096+cell][256] ----------

__global__ __launch_bounds__(256) void k_db(const float* __restrict__ x,
                                            const int* __restrict__ idxT,
                                            float* __restrict__ db) {
  int t = blockIdx.x * 256 + threadIdx.x;
  int mi = t & 31;
  int cellLocal = (t >> 5) & 4095;
  int b = t >> 17;
  int g = idxT[(size_t)b * NPTS + cellLocal * 32 + mi];
  const float* src = x + ((size_t)b * NPTS + g) * 8;
  float4 lo = *(const float4*)(src);
  float4 hi = *(const float4*)(src + 4);
  float* dst = db + (size_t)t * 8;
  *(float4*)(dst) = lo;
  *(float4*)(dst + 4) = hi;
}

// ---------- final bicubic: lanes=channels, LDS transpose ----------

__global__ __launch_bounds__(256) void k_final3(const float* __restrict__ db,
                                                const int* __restrict__ ind,
                                                const int* __restrict__ ind0t,
                                                float* __restrict__ outp) {
#pragma clang fp contract(off)
  __shared__ int sRI[256], sCI[256];
  __shared__ float sWH[256], sWW[256];
  __shared__ float tile[64][65];

  const int bid = blockIdx.x;
  const int b = bid >> 8;
  const int p = (bid >> 2) & 63;
  const int cg = bid & 3;
  const int tid = threadIdx.x;
  const float R = (float)(65.0 / 131.0);

  if (tid < 64) {
    int qt = tid;
    int wstar = ind[((size_t)b * 64 + qt) * 64 + p];
    int hstar = ind0t[((size_t)b * 64 + qt) * 132 + wstar];
    float posh = (float)hstar * R;
    int i0h = (int)floorf(posh);
    float frh = posh - (float)i0h;
    float posw = (float)wstar * R;
    int i0w = (int)floorf(posw);
    float frw = posw - (float)i0w;
#pragma unroll
    for (int k = 0; k < 4; ++k) {
      int I = i0h + k - 1;
      I = I < 0 ? 0 : (I > 65 ? 65 : I);
      int rI = I - 1;
      sRI[qt * 4 + k] = rI < 0 ? 0 : (rI > 63 ? 63 : rI);
      sWH[qt * 4 + k] = cubw(frh - (float)(k - 1));
      int J = i0w + k - 1;
      J = J < 0 ? 0 : (J > 65 ? 65 : J);
      int cJ = J - 1;
      sCI[qt * 4 + k] = cJ < 0 ? 0 : (cJ > 63 ? 63 : cJ);
      sWW[qt * 4 + k] = cubw(frw - (float)(k - 1));
    }
  }
  __syncthreads();

  const int wave = tid >> 6, lane = tid & 63;
  const int ch = cg * 64 + lane;
  const size_t dbb = (size_t)(b * 4096) * 256 + ch;

  for (int s = 0; s < 16; ++s) {
    int qt = wave * 16 + s;
    float a = 0.0f;
#pragma unroll
    for (int l = 0; l < 4; ++l) {
      float t = 0.0f;
#pragma unroll
      for (int k = 0; k < 4; ++k) {
        float v = db[dbb + (size_t)(sRI[qt * 4 + k] * 64 + sCI[qt * 4 + l]) * 256];
        t = fmaf(v, sWH[qt * 4 + k], t);
      }
      a = fmaf(t, sWW[qt * 4 + l], a);
    }
    tile[qt][lane] = a;
  }
  __syncthreads();

  for (int it = 0; it < 16; ++it) {
    int qt2 = tid & 63;
    int cc = (tid >> 6) * 16 + it;
    outp[(((size_t)b * 256 + cg * 64 + cc) * 64 + p) * 64 + qt2] = tile[qt2][cc];
  }
}

// ---------- launch ----------

extern "C" void kernel_launch(void* const* d_in, const int* in_sizes, int n_in,
                              void* d_out, int out_size, void* d_ws, size_t ws_size,
                              hipStream_t stream) {
  (void)n_in; (void)out_size; (void)ws_size;
  const float* x;
  const float* coords;
  if (in_sizes[0] == 8388608) {
    x = (const float*)d_in[0];
    coords = (const float*)d_in[1];
  } else {
    coords = (const float*)d_in[0];
    x = (const float*)d_in[1];
  }
  float* outp = (float*)d_out;
  char* ws = (char*)d_ws;

  uint32_t* KA = (uint32_t*)(ws + 0);          // 4 MB
  uint32_t* KB = (uint32_t*)(ws + 4194304);    // 4 MB
  uint32_t* HIST = (uint32_t*)(ws + 8388608);  // 256 KB
  int* IDX1 = (int*)(ws + 8650752);            // 4 MB
  float* CP = (float*)(ws + 0);                // 278784 B (after radix dead)
  float* DB = (float*)(ws + 0);                // 33.5 MB (after CP consumed)

  size_t P = 33554432;
  int* IDXT = (int*)(ws + P);          P += 4194304;
  float* CM = (float*)(ws + P);        P += 262144;
  int* IND0T = (int*)(ws + P);         P += 270336;
  float* C1SEL = (float*)(ws + P);     P += 270336;
  int* IND = (int*)(ws + P);           P += 131072;
  float* QB1 = (float*)(ws + P);       P += 2048;

  // P0: coords -> KA (shift 0, fused key calc)
  k_radix_hist0<<<256, 256, 0, stream>>>(coords, HIST);
  k_scan2<<<8, 256, 0, stream>>>(HIST, 256);
  k_radix_scatter0<<<256, 256, 0, stream>>>(coords, KA, HIST);
  // P1: KA -> KB (shift 8)
  k_radix_hist<<<256, 256, 0, stream>>>(KA, HIST, 8, 0);
  k_scan2<<<8, 256, 0, stream>>>(HIST, 256);
  k_radix_scatter<<<256, 256, 0, stream>>>(KA, KB, HIST, 8, 0);
  // P2: KB -> KA (shift 16)
  k_radix_hist<<<256, 256, 0, stream>>>(KB, HIST, 16, 0);
  k_scan2<<<8, 256, 0, stream>>>(HIST, 256);
  k_radix_scatter<<<256, 256, 0, stream>>>(KB, KA, HIST, 16, 0);
  // P3 (batch 0 only): KA -> KB (shift 24)
  k_radix_hist<<<32, 256, 0, stream>>>(KA, HIST, 24, 0);
  k_scan2<<<1, 256, 0, stream>>>(HIST, 256);
  k_radix_scatter<<<32, 256, 0, stream>>>(KA, KB, HIST, 24, 0);
  // batch 0 sorted in KB; batches>=1 sorted in KA
  k_quantile1<<<8, 64, 0, stream>>>(KB, KA, QB1);

  k_bhist<<<256, 256, 0, stream>>>(coords, QB1, HIST);
  k_scan2<<<8, 256, 0, stream>>>(HIST, 64);
  k_bscatter<<<256, 256, 0, stream>>>(coords, QB1, HIST, IDX1);

  k_level2<<<512, 256, 0, stream>>>(IDX1, coords, IDXT, CM);

  k_cp2<<<8, 256, 0, stream>>>(CM, CP);
  k_selA<<<1056, 128, 0, stream>>>(CP, IND0T, C1SEL);
  k_sel1b<<<512, 64, 0, stream>>>(C1SEL, IND);

  k_db<<<4096, 256, 0, stream>>>(x, IDXT, DB);
  k_final3<<<2048, 256, 0, stream>>>(DB, IND, IND0T, outp);
}

// Round 18
// 230.533 us; speedup vs baseline: 1.9055x; 1.0143x over previous
//
#include <hip/hip_runtime.h>
#include <stdint.h>

#define NPTS 131072

// ---------- helpers (XLA:GPU contraction semantics: fma-fused) ----------

__device__ __forceinline__ float cubw(float t) {
#pragma clang fp contract(off)
  float at = fabsf(t);
  if (at <= 1.0f) {
    float u = fmaf(1.25f, at, -2.25f);
    u = u * at;
    return fmaf(u, at, 1.0f);
  } else if (at < 2.0f) {
    float u = at - 5.0f;
    u = fmaf(u, at, 8.0f);
    u = fmaf(u, at, -4.0f);
    return u * -0.75f;
  }
  return 0.0f;
}

__device__ __forceinline__ float quant_frac(int t) {
#pragma clang fp contract(off)
  return (float)(t + 1) * 0.015625f;
}

__device__ __forceinline__ float grid_val(int i) {
#pragma clang fp contract(off)
  return (float)i * (1.0f / 63.0f);
}

__device__ __forceinline__ float jax_quantile_lerp(float vlo, float vhi, float q) {
#pragma clang fp contract(off)
  float lowf = floorf(q);
  float highf = ceilf(q);
  float hw = q - lowf;
  float lw = highf - q;
  float bh = vhi * hw;
  return fmaf(vlo, lw, bh);
}

__device__ __forceinline__ float bilerp1(float a, float b, float w) {
#pragma clang fp contract(off)
  float omw = 1.0f - w;
  float bw = b * w;
  return fmaf(a, omw, bw);
}

template <int NB>
__device__ __forceinline__ unsigned long long match_mask(uint32_t d) {
  unsigned long long m = ~0ull;
#pragma unroll
  for (int i = 0; i < NB; ++i) {
    unsigned long long bal = __ballot((int)((d >> i) & 1u));
    m &= ((d >> i) & 1u) ? bal : ~bal;
  }
  return m;
}

// adjusted level-1 key: u(fl(x + 8b)) - u(8b)  (order-preserving)
__device__ __forceinline__ uint32_t l1key(const float* coords, int batch, int idx) {
#pragma clang fp contract(off)
  float off = (float)(8 * batch);
  float c = coords[(size_t)(batch * 2) * NPTS + idx] + off;
  return __float_as_uint(c) - __float_as_uint(off);
}

// ---------- parallel exclusive scan over [bins][32] per batch ----------

__global__ __launch_bounds__(256) void k_scan2(uint32_t* __restrict__ buf, int bins) {
  __shared__ uint32_t lds[256 * 33];
  __shared__ uint32_t wavetot[4];
  const int batch = blockIdx.x, tid = threadIdx.x;
  const int lane = tid & 63, wv = tid >> 6;
  uint32_t* p = buf + (size_t)batch * bins * 32;
  const int n = bins * 32;
  for (int i = tid; i < n; i += 256) {
    int d = i >> 5, blk = i & 31;
    lds[d * 33 + blk] = p[i];
  }
  __syncthreads();
  uint32_t mysum = 0;
  if (tid < bins) {
#pragma unroll 8
    for (int blk = 0; blk < 32; ++blk) mysum += lds[tid * 33 + blk];
  }
  uint32_t inc = mysum;
#pragma unroll
  for (int d2 = 1; d2 < 64; d2 <<= 1) {
    uint32_t u = __shfl_up(inc, d2, 64);
    if (lane >= d2) inc += u;
  }
  if (lane == 63) wavetot[wv] = inc;
  __syncthreads();
  uint32_t woff = 0;
  for (int w2 = 0; w2 < wv; ++w2) woff += wavetot[w2];
  uint32_t binbase = inc - mysum + woff;
  if (tid < bins) {
    uint32_t run = binbase;
#pragma unroll 8
    for (int blk = 0; blk < 32; ++blk) {
      uint32_t t = lds[tid * 33 + blk];
      p[tid * 32 + blk] = run;
      run += t;
    }
  }
}

// ---------- LSD radix (8-bit): generic hist/scatter on materialized keys ----------

__global__ __launch_bounds__(256) void k_radix_hist(const uint32_t* __restrict__ in,
                                                    uint32_t* __restrict__ hist, int shift,
                                                    int batch0) {
  __shared__ uint32_t h[256];
  int tid = threadIdx.x;
  int batch = (blockIdx.x >> 5) + batch0, blk = blockIdx.x & 31;
  h[tid] = 0;
  __syncthreads();
  const uint32_t* keys = in + (size_t)batch * NPTS + (size_t)blk * 4096;
  for (int r = 0; r < 16; ++r) {
    uint32_t d = (keys[r * 256 + tid] >> shift) & 255u;
    atomicAdd(&h[d], 1u);
  }
  __syncthreads();
  hist[((size_t)batch * 256 + tid) * 32 + blk] = h[tid];
}

__global__ __launch_bounds__(256) void k_radix_scatter(const uint32_t* __restrict__ in,
                                                       uint32_t* __restrict__ out,
                                                       const uint32_t* __restrict__ base,
                                                       int shift, int batch0) {
  __shared__ uint32_t whist[4 * 256];
  int tid = threadIdx.x;
  int wv = tid >> 6, lane = tid & 63;
  int batch = (blockIdx.x >> 5) + batch0, blk = blockIdx.x & 31;
  size_t batchbase = (size_t)batch * NPTS;
  const uint32_t* src = in + batchbase + (size_t)blk * 4096 + (size_t)wv * 1024;

  for (int i = tid; i < 4 * 256; i += 256) whist[i] = 0;
  __syncthreads();

  uint32_t keyv[16], posv[16];
#pragma unroll
  for (int r = 0; r < 16; ++r) {
    uint32_t key = src[r * 64 + lane];
    uint32_t d = (key >> shift) & 255u;
    unsigned long long m = match_mask<8>(d);
    unsigned long long below = m & ((1ull << lane) - 1ull);
    uint32_t rank = (uint32_t)__popcll(below);
    uint32_t cnt = (uint32_t)__popcll(m);
    uint32_t bse = whist[wv * 256 + d];
    if (below == 0ull) whist[wv * 256 + d] = bse + cnt;
    keyv[r] = key;
    posv[r] = bse + rank;
  }
  __syncthreads();
  {
    uint32_t a0 = whist[tid], a1 = whist[256 + tid], a2 = whist[512 + tid];
    whist[tid] = 0;
    whist[256 + tid] = a0;
    whist[512 + tid] = a0 + a1;
    whist[768 + tid] = a0 + a1 + a2;
  }
  __syncthreads();
  const uint32_t* bb = base + (size_t)batch * 8192;
#pragma unroll
  for (int r = 0; r < 16; ++r) {
    uint32_t key = keyv[r];
    uint32_t d = (key >> shift) & 255u;
    uint32_t pos = bb[d * 32 + blk] + whist[wv * 256 + d] + posv[r];
    out[batchbase + pos] = key;
  }
}

// pass-0 variants: compute adjusted key from coords inline

__global__ __launch_bounds__(256) void k_radix_hist0(const float* __restrict__ coords,
                                                     uint32_t* __restrict__ hist) {
  __shared__ uint32_t h[256];
  int tid = threadIdx.x;
  int batch = blockIdx.x >> 5, blk = blockIdx.x & 31;
  h[tid] = 0;
  __syncthreads();
  for (int r = 0; r < 16; ++r) {
    uint32_t d = l1key(coords, batch, blk * 4096 + r * 256 + tid) & 255u;
    atomicAdd(&h[d], 1u);
  }
  __syncthreads();
  hist[((size_t)batch * 256 + tid) * 32 + blk] = h[tid];
}

__global__ __launch_bounds__(256) void k_radix_scatter0(const float* __restrict__ coords,
                                                        uint32_t* __restrict__ out,
                                                        const uint32_t* __restrict__ base) {
  __shared__ uint32_t whist[4 * 256];
  int tid = threadIdx.x;
  int wv = tid >> 6, lane = tid & 63;
  int batch = blockIdx.x >> 5, blk = blockIdx.x & 31;
  size_t batchbase = (size_t)batch * NPTS;

  for (int i = tid; i < 4 * 256; i += 256) whist[i] = 0;
  __syncthreads();

  uint32_t keyv[16], posv[16];
#pragma unroll
  for (int r = 0; r < 16; ++r) {
    uint32_t key = l1key(coords, batch, blk * 4096 + wv * 1024 + r * 64 + lane);
    uint32_t d = key & 255u;
    unsigned long long m = match_mask<8>(d);
    unsigned long long below = m & ((1ull << lane) - 1ull);
    uint32_t rank = (uint32_t)__popcll(below);
    uint32_t cnt = (uint32_t)__popcll(m);
    uint32_t bse = whist[wv * 256 + d];
    if (below == 0ull) whist[wv * 256 + d] = bse + cnt;
    keyv[r] = key;
    posv[r] = bse + rank;
  }
  __syncthreads();
  {
    uint32_t a0 = whist[tid], a1 = whist[256 + tid], a2 = whist[512 + tid];
    whist[tid] = 0;
    whist[256 + tid] = a0;
    whist[512 + tid] = a0 + a1;
    whist[768 + tid] = a0 + a1 + a2;
  }
  __syncthreads();
  const uint32_t* bb = base + (size_t)batch * 8192;
#pragma unroll
  for (int r = 0; r < 16; ++r) {
    uint32_t key = keyv[r];
    uint32_t d = key & 255u;
    uint32_t pos = bb[d * 32 + blk] + whist[wv * 256 + d] + posv[r];
    out[batchbase + pos] = key;
  }
}

// ---------- level-1 quantiles (batch 0 sorted in sA; batches>=1 in sB) ----------

__global__ __launch_bounds__(64) void k_quantile1(const uint32_t* __restrict__ sA,
                                                  const uint32_t* __restrict__ sB,
                                                  float* __restrict__ qb1) {
#pragma clang fp contract(off)
  int batch = blockIdx.x, t = threadIdx.x;
  if (t >= 63) return;
  float qv = quant_frac(t);
  float q = qv * 131071.0f;
  int lo = (int)floorf(q);
  const uint32_t* s = (batch == 0 ? sA : sB) + (size_t)batch * NPTS;
  uint32_t u0 = __float_as_uint((float)(8 * batch));
  float vlo = __uint_as_float(s[lo] + u0);
  float vhi = __uint_as_float(s[lo + 1] + u0);
  qb1[batch * 64 + t] = jax_quantile_lerp(vlo, vhi, q);
}

// ---------- level-1 stable counting sort by bucket ----------

__global__ __launch_bounds__(256) void k_bhist(const float* __restrict__ coords,
                                               const float* __restrict__ qb1,
                                               uint32_t* __restrict__ hist) {
#pragma clang fp contract(off)
  __shared__ uint32_t h[64];
  __shared__ float qb[63];
  int tid = threadIdx.x;
  int batch = blockIdx.x >> 5, blk = blockIdx.x & 31;
  if (tid < 64) h[tid] = 0;
  if (tid >= 64 && tid < 127) qb[tid - 64] = qb1[batch * 64 + (tid - 64)];
  __syncthreads();
  const float* c = coords + (size_t)(batch * 2) * NPTS + (size_t)blk * 4096;
  float off = (float)(8 * batch);
  for (int r = 0; r < 16; ++r) {
    float v = c[r * 256 + tid] + off;
    uint32_t d = 0;
#pragma unroll
    for (int k = 0; k < 63; ++k) d += (qb[k] <= v) ? 1u : 0u;
    atomicAdd(&h[d], 1u);
  }
  __syncthreads();
  if (tid < 64) hist[((size_t)batch * 64 + tid) * 32 + blk] = h[tid];
}

__global__ __launch_bounds__(256) void k_bscatter(const float* __restrict__ coords,
                                                  const float* __restrict__ qb1,
                                                  const uint32_t* __restrict__ base,
                                                  int* __restrict__ idxout) {
#pragma clang fp contract(off)
  __shared__ uint32_t whist[4 * 64];
  __shared__ float qb[63];
  int tid = threadIdx.x;
  int wv = tid >> 6, lane = tid & 63;
  int batch = blockIdx.x >> 5, blk = blockIdx.x & 31;
  if (tid < 4 * 64) whist[tid] = 0;
  if (tid >= 192 && tid < 255) qb[tid - 192] = qb1[batch * 64 + (tid - 192)];
  __syncthreads();
  const float* c = coords + (size_t)(batch * 2) * NPTS + (size_t)blk * 4096 + (size_t)wv * 1024;
  float off = (float)(8 * batch);
  uint32_t bkv[16], rkv[16];
#pragma unroll
  for (int r = 0; r < 16; ++r) {
    float v = c[r * 64 + lane] + off;
    uint32_t d = 0;
#pragma unroll
    for (int k = 0; k < 63; ++k) d += (qb[k] <= v) ? 1u : 0u;
    unsigned long long m = match_mask<6>(d);
    unsigned long long below = m & ((1ull << lane) - 1ull);
    uint32_t rank = (uint32_t)__popcll(below);
    uint32_t cnt = (uint32_t)__popcll(m);
    uint32_t bse = whist[wv * 64 + d];
    if (below == 0ull) whist[wv * 64 + d] = bse + cnt;
    bkv[r] = d;
    rkv[r] = bse + rank;
  }
  __syncthreads();
  if (tid < 64) {
    uint32_t a0 = whist[tid], a1 = whist[64 + tid], a2 = whist[128 + tid];
    whist[tid] = 0;
    whist[64 + tid] = a0;
    whist[128 + tid] = a0 + a1;
    whist[192 + tid] = a0 + a1 + a2;
  }
  __syncthreads();
  const uint32_t* bb = base + (size_t)batch * 2048;
  int ibase = blk * 4096 + wv * 1024;
#pragma unroll
  for (int r = 0; r < 16; ++r) {
    uint32_t d = bkv[r];
    uint32_t pos = bb[d * 32 + blk] + whist[wv * 64 + d] + rkv[r];
    idxout[(size_t)batch * NPTS + pos] = ibase + r * 64 + lane;
  }
}

// ---------- level-2: adjusted-key radix (1/2/4 passes) + bucket sort ----------

__global__ __launch_bounds__(256) void k_level2(const int* __restrict__ idx1,
                                                const float* __restrict__ coords,
                                                int* __restrict__ idxT,
                                                float* __restrict__ cm) {
#pragma clang fp contract(off)
  __shared__ int gidx[2048];
  __shared__ float ckey[2048];
  __shared__ uint32_t sbA[2048];
  __shared__ uint32_t sbB[2048];
  __shared__ uint32_t whist[4 * 256];
  __shared__ uint32_t base[256];
  __shared__ uint32_t wavetot[4];
  __shared__ float qb[63];

  const int tid = threadIdx.x;
  const int wv = tid >> 6, lane = tid & 63;
  const int row = blockIdx.x;
  const int b = row >> 6, i1 = row & 63;
  const float offf = (float)(512 * row);
  const uint32_t u0 = __float_as_uint(offf);

  for (int j = tid; j < 2048; j += 256) {
    int g = idx1[(size_t)b * NPTS + i1 * 2048 + j];
    gidx[j] = g;
    float cv = coords[((size_t)(b * 2 + 1)) * NPTS + g] + offf;
    ckey[j] = cv;
    sbA[j] = __float_as_uint(cv) - u0;
  }
  __syncthreads();

  // adjusted key bound: 2^(23-e), e = exp(offf). row>=128 -> <=128 (1 pass);
  // row>=1 -> <=2^14 (2 passes); row 0 -> 4 passes.
  const int npass = (row == 0) ? 4 : (row >= 128 ? 1 : 2);
  uint32_t* A = sbA;
  uint32_t* B = sbB;
  for (int pass = 0; pass < npass; ++pass) {
    const int shift = pass * 8;
    for (int i = tid; i < 1024; i += 256) whist[i] = 0;
    __syncthreads();
    uint32_t keyv[8], posv[8];
#pragma unroll
    for (int r = 0; r < 8; ++r) {
      int j = wv * 512 + r * 64 + lane;
      uint32_t key = A[j];
      uint32_t d = (key >> shift) & 255u;
      unsigned long long m = match_mask<8>(d);
      unsigned long long below = m & ((1ull << lane) - 1ull);
      uint32_t rank = (uint32_t)__popcll(below);
      uint32_t cnt = (uint32_t)__popcll(m);
      uint32_t bse = whist[wv * 256 + d];
      if (below == 0ull) whist[wv * 256 + d] = bse + cnt;
      keyv[r] = key;
      posv[r] = bse + rank;
    }
    __syncthreads();
    {
      uint32_t a0 = whist[tid], a1 = whist[256 + tid], a2 = whist[512 + tid],
               a3 = whist[768 + tid];
      base[tid] = a0 + a1 + a2 + a3;
      whist[tid] = 0;
      whist[256 + tid] = a0;
      whist[512 + tid] = a0 + a1;
      whist[768 + tid] = a0 + a1 + a2;
    }
    __syncthreads();
    {
      uint32_t v = base[tid];
      uint32_t inc = v;
#pragma unroll
      for (int d2 = 1; d2 < 64; d2 <<= 1) {
        uint32_t u = __shfl_up(inc, d2, 64);
        if (lane >= d2) inc += u;
      }
      if (lane == 63) wavetot[wv] = inc;
      __syncthreads();
      uint32_t woff = 0;
      for (int w2 = 0; w2 < wv; ++w2) woff += wavetot[w2];
      base[tid] = inc - v + woff;
    }
    __syncthreads();
#pragma unroll
    for (int r = 0; r < 8; ++r) {
      uint32_t d = (keyv[r] >> shift) & 255u;
      B[base[d] + whist[wv * 256 + d] + posv[r]] = keyv[r];
    }
    __syncthreads();
    uint32_t* t = A;
    A = B;
    B = t;
  }
  // A points at the sorted buffer (sbA for even npass, sbB for odd)

  if (tid < 63) {
    float qv = quant_frac(tid);
    float q = qv * 2047.0f;
    int lo = (int)floorf(q);
    float vlo = __uint_as_float(A[lo] + u0);
    float vhi = __uint_as_float(A[lo + 1] + u0);
    qb[tid] = jax_quantile_lerp(vlo, vhi, q);
  }
  for (int i = tid; i < 256; i += 256) whist[i] = 0;
  __syncthreads();

  // stable counting sort by bucket; perm written into sbB (sorted keys dead now)
  uint32_t dv[8], pv[8];
#pragma unroll
  for (int r = 0; r < 8; ++r) {
    int j = wv * 512 + r * 64 + lane;
    float cv = ckey[j];
    uint32_t d = 0;
#pragma unroll
    for (int k = 0; k < 63; ++k) d += (qb[k] <= cv) ? 1u : 0u;
    unsigned long long m = match_mask<6>(d);
    unsigned long long below = m & ((1ull << lane) - 1ull);
    uint32_t rank = (uint32_t)__popcll(below);
    uint32_t cnt = (uint32_t)__popcll(m);
    uint32_t bse = whist[wv * 64 + d];
    if (below == 0ull) whist[wv * 64 + d] = bse + cnt;
    dv[r] = d;
    pv[r] = bse + rank;
  }
  __syncthreads();
  if (tid < 64) {
    uint32_t a0 = whist[tid], a1 = whist[64 + tid], a2 = whist[128 + tid],
             a3 = whist[192 + tid];
    base[tid] = a0 + a1 + a2 + a3;
    whist[tid] = 0;
    whist[64 + tid] = a0;
    whist[128 + tid] = a0 + a1;
    whist[192 + tid] = a0 + a1 + a2;
  }
  __syncthreads();
  if (wv == 0) {
    uint32_t v = base[lane];
    uint32_t inc = v;
#pragma unroll
    for (int d2 = 1; d2 < 64; d2 <<= 1) {
      uint32_t u = __shfl_up(inc, d2, 64);
      if (lane >= d2) inc += u;
    }
    base[lane] = inc - v;
  }
  __syncthreads();
#pragma unroll
  for (int r = 0; r < 8; ++r) {
    int j = wv * 512 + r * 64 + lane;
    uint32_t pos = base[dv[r]] + whist[wv * 64 + dv[r]] + pv[r];
    sbB[pos] = (uint32_t)j;
  }
  __syncthreads();

  for (int p = tid; p < 2048; p += 256)
    idxT[(size_t)b * NPTS + i1 * 2048 + p] = gidx[sbB[p]];

  if (tid < 128) {
    int i2 = tid >> 1, d = tid & 1;
    float v[32];
#pragma unroll
    for (int m2 = 0; m2 < 32; ++m2)
      v[m2] = coords[((size_t)(b * 2 + d)) * NPTS + gidx[sbB[i2 * 32 + m2]]];
#pragma unroll
    for (int r = 0; r < 32; ++r) {
#pragma unroll
      for (int i = (r & 1); i + 1 < 32; i += 2) {
        float a = v[i], c2 = v[i + 1];
        v[i] = fminf(a, c2);
        v[i + 1] = fmaxf(a, c2);
      }
    }
    cm[(((size_t)(b * 2 + d)) * 64 + i1) * 64 + i2] = v[15];
  }
}

// ---------- padded coord grid CP[b*2+d][66][66] ----------

__global__ __launch_bounds__(256) void k_cp2(const float* __restrict__ cm,
                                             float* __restrict__ cp) {
#pragma clang fp contract(off)
  __shared__ float cp0[66][66];
  __shared__ float cp1[66][66];
  const int b = blockIdx.x;
  const int tid = threadIdx.x;
  const float* m0 = cm + (size_t)(b * 2) * 4096;
  const float* m1 = cm + (size_t)(b * 2 + 1) * 4096;

  for (int i = tid; i < 4096; i += 256) {
    int i1 = i >> 6, i2 = i & 63;
    cp0[1 + i1][1 + i2] = m0[i];
    cp1[1 + i1][1 + i2] = m1[i];
  }
  __syncthreads();

  if (tid < 64) {
    int i2 = tid;
    float mn = m0[i2], mx = m0[i2];
    for (int i1 = 1; i1 < 64; ++i1) {
      float v = m0[i1 * 64 + i2];
      mn = fminf(mn, v);
      mx = fmaxf(mx, v);
    }
    cp0[0][1 + i2] = mn - 0.5f;
    cp0[65][1 + i2] = mx + 0.5f;
  } else if (tid < 128) {
    int i1 = tid - 64;
    float mn = m1[i1 * 64], mx = m1[i1 * 64];
    for (int i2 = 1; i2 < 64; ++i2) {
      float v = m1[i1 * 64 + i2];
      mn = fminf(mn, v);
      mx = fmaxf(mx, v);
    }
    cp1[1 + i1][0] = mn - 0.5f;
    cp1[1 + i1][65] = mx + 0.5f;
  }
  __syncthreads();

  if (tid < 66) {
    cp0[tid][0] = cp0[tid][1];
    cp0[tid][65] = cp0[tid][64];
  } else if (tid < 132) {
    int w = tid - 66;
    cp1[0][w] = cp1[1][w];
    cp1[65][w] = cp1[64][w];
  }
  __syncthreads();

  for (int e = tid; e < 4356; e += 256) {
    int h = e / 66, w = e % 66;
    cp[((size_t)(b * 2) * 66 + h) * 66 + w] = cp0[h][w];
    cp[((size_t)(b * 2 + 1) * 66 + h) * 66 + w] = cp1[h][w];
  }
}

// ---------- fused bilinear column + argmin0 per (b,w) ----------

__global__ __launch_bounds__(128) void k_selA(const float* __restrict__ cp,
                                              int* __restrict__ ind0t,
                                              float* __restrict__ c1sel) {
#pragma clang fp contract(off)
  __shared__ float col0[132], col1[132];
  const int bw = blockIdx.x;
  const int b = bw / 132, wp = bw % 132;
  const int tid = threadIdx.x;
  const float R = (float)(65.0 / 131.0);

  float posw = (float)wp * R;
  int j0 = (int)floorf(posw);
  if (j0 < 0) j0 = 0;
  if (j0 > 65) j0 = 65;
  int j1 = j0 + 1;
  if (j1 > 65) j1 = 65;
  float wu = posw - (float)j0;

  const float* p0 = cp + (size_t)(b * 2) * 4356;
  const float* p1 = cp + (size_t)(b * 2 + 1) * 4356;

  for (int hp = tid; hp < 132; hp += 128) {
    float posh = (float)hp * R;
    int r0 = (int)floorf(posh);
    if (r0 < 0) r0 = 0;
    if (r0 > 65) r0 = 65;
    int r1 = r0 + 1;
    if (r1 > 65) r1 = 65;
    float wt = posh - (float)r0;
    float ta0 = bilerp1(p0[r0 * 66 + j0], p0[r1 * 66 + j0], wt);
    float tb0 = bilerp1(p0[r0 * 66 + j1], p0[r1 * 66 + j1], wt);
    float ta1 = bilerp1(p1[r0 * 66 + j0], p1[r1 * 66 + j0], wt);
    float tb1 = bilerp1(p1[r0 * 66 + j1], p1[r1 * 66 + j1], wt);
    col0[hp] = bilerp1(ta0, tb0, wu);
    col1[hp] = bilerp1(ta1, tb1, wu);
  }
  __syncthreads();
  if (tid < 64) {
    float gv = grid_val(tid);
    float best = fabsf(col0[0] - gv);
    int bi = 0;
    for (int h = 1; h < 132; ++h) {
      float d2 = fabsf(col0[h] - gv);
      if (d2 < best) { best = d2; bi = h; }
    }
    ind0t[((size_t)b * 64 + tid) * 132 + wp] = bi;
    c1sel[((size_t)b * 64 + tid) * 132 + wp] = col1[bi];
  }
}

__global__ __launch_bounds__(64) void k_sel1b(const float* __restrict__ c1sel,
                                              int* __restrict__ ind) {
#pragma clang fp contract(off)
  __shared__ float rv[132];
  int b = blockIdx.x >> 6, g0 = blockIdx.x & 63;
  int tid = threadIdx.x;
  for (int w = tid; w < 132; w += 64) rv[w] = c1sel[((size_t)b * 64 + g0) * 132 + w];
  __syncthreads();
  float gv = grid_val(tid);
  float best = fabsf(rv[0] - gv);
  int bi = 0;
  for (int w = 1; w < 132; ++w) {
    float d2 = fabsf(rv[w] - gv);
    if (d2 < best) { best = d2; bi = w; }
  }
  ind[((size_t)b * 64 + g0) * 64 + tid] = bi;
}

// ---------- gather x into cell-contiguous DB[b*4096+cell][256] ----------

__global__ __launch_bounds__(256) void k_db(const float* __restrict__ x,
                                            const int* __restrict__ idxT,
                                            float* __restrict__ db) {
  int t = blockIdx.x * 256 + threadIdx.x;
  int mi = t & 31;
  int cellLocal = (t >> 5) & 4095;
  int b = t >> 17;
  int g = idxT[(size_t)b * NPTS + cellLocal * 32 + mi];
  const float* src = x + ((size_t)b * NPTS + g) * 8;
  float4 lo = *(const float4*)(src);
  float4 hi = *(const float4*)(src + 4);
  float* dst = db + (size_t)t * 8;
  *(float4*)(dst) = lo;
  *(float4*)(dst + 4) = hi;
}

// ---------- final bicubic: lanes=channels, LDS transpose ----------

__global__ __launch_bounds__(256) void k_final3(const float* __restrict__ db,
                                                const int* __restrict__ ind,
                                                const int* __restrict__ ind0t,
                                                float* __restrict__ outp) {
#pragma clang fp contract(off)
  __shared__ int sRI[256], sCI[256];
  __shared__ float sWH[256], sWW[256];
  __shared__ float tile[64][65];

  const int bid = blockIdx.x;
  const int b = bid >> 8;
  const int p = (bid >> 2) & 63;
  const int cg = bid & 3;
  const int tid = threadIdx.x;
  const float R = (float)(65.0 / 131.0);

  if (tid < 64) {
    int qt = tid;
    int wstar = ind[((size_t)b * 64 + qt) * 64 + p];
    int hstar = ind0t[((size_t)b * 64 + qt) * 132 + wstar];
    float posh = (float)hstar * R;
    int i0h = (int)floorf(posh);
    float frh = posh - (float)i0h;
    float posw = (float)wstar * R;
    int i0w = (int)floorf(posw);
    float frw = posw - (float)i0w;
#pragma unroll
    for (int k = 0; k < 4; ++k) {
      int I = i0h + k - 1;
      I = I < 0 ? 0 : (I > 65 ? 65 : I);
      int rI = I - 1;
      sRI[qt * 4 + k] = rI < 0 ? 0 : (rI > 63 ? 63 : rI);
      sWH[qt * 4 + k] = cubw(frh - (float)(k - 1));
      int J = i0w + k - 1;
      J = J < 0 ? 0 : (J > 65 ? 65 : J);
      int cJ = J - 1;
      sCI[qt * 4 + k] = cJ < 0 ? 0 : (cJ > 63 ? 63 : cJ);
      sWW[qt * 4 + k] = cubw(frw - (float)(k - 1));
    }
  }
  __syncthreads();

  const int wave = tid >> 6, lane = tid & 63;
  const int ch = cg * 64 + lane;
  const size_t dbb = (size_t)(b * 4096) * 256 + ch;

  for (int s = 0; s < 16; ++s) {
    int qt = wave * 16 + s;
    float a = 0.0f;
#pragma unroll
    for (int l = 0; l < 4; ++l) {
      float t = 0.0f;
#pragma unroll
      for (int k = 0; k < 4; ++k) {
        float v = db[dbb + (size_t)(sRI[qt * 4 + k] * 64 + sCI[qt * 4 + l]) * 256];
        t = fmaf(v, sWH[qt * 4 + k], t);
      }
      a = fmaf(t, sWW[qt * 4 + l], a);
    }
    tile[qt][lane] = a;
  }
  __syncthreads();

  for (int it = 0; it < 16; ++it) {
    int qt2 = tid & 63;
    int cc = (tid >> 6) * 16 + it;
    outp[(((size_t)b * 256 + cg * 64 + cc) * 64 + p) * 64 + qt2] = tile[qt2][cc];
  }
}

// ---------- launch ----------

extern "C" void kernel_launch(void* const* d_in, const int* in_sizes, int n_in,
                              void* d_out, int out_size, void* d_ws, size_t ws_size,
                              hipStream_t stream) {
  (void)n_in; (void)out_size; (void)ws_size;
  const float* x;
  const float* coords;
  if (in_sizes[0] == 8388608) {
    x = (const float*)d_in[0];
    coords = (const float*)d_in[1];
  } else {
    coords = (const float*)d_in[0];
    x = (const float*)d_in[1];
  }
  float* outp = (float*)d_out;
  char* ws = (char*)d_ws;

  uint32_t* KA = (uint32_t*)(ws + 0);
  uint32_t* KB = (uint32_t*)(ws + 4194304);
  uint32_t* HIST = (uint32_t*)(ws + 8388608);
  int* IDX1 = (int*)(ws + 8650752);
  float* CP = (float*)(ws + 0);
  float* DB = (float*)(ws + 0);

  size_t P = 33554432;
  int* IDXT = (int*)(ws + P);          P += 4194304;
  float* CM = (float*)(ws + P);        P += 262144;
  int* IND0T = (int*)(ws + P);         P += 270336;
  float* C1SEL = (float*)(ws + P);     P += 270336;
  int* IND = (int*)(ws + P);           P += 131072;
  float* QB1 = (float*)(ws + P);       P += 2048;

  k_radix_hist0<<<256, 256, 0, stream>>>(coords, HIST);
  k_scan2<<<8, 256, 0, stream>>>(HIST, 256);
  k_radix_scatter0<<<256, 256, 0, stream>>>(coords, KA, HIST);
  k_radix_hist<<<256, 256, 0, stream>>>(KA, HIST, 8, 0);
  k_scan2<<<8, 256, 0, stream>>>(HIST, 256);
  k_radix_scatter<<<256, 256, 0, stream>>>(KA, KB, HIST, 8, 0);
  k_radix_hist<<<256, 256, 0, stream>>>(KB, HIST, 16, 0);
  k_scan2<<<8, 256, 0, stream>>>(HIST, 256);
  k_radix_scatter<<<256, 256, 0, stream>>>(KB, KA, HIST, 16, 0);
  k_radix_hist<<<32, 256, 0, stream>>>(KA, HIST, 24, 0);
  k_scan2<<<1, 256, 0, stream>>>(HIST, 256);
  k_radix_scatter<<<32, 256, 0, stream>>>(KA, KB, HIST, 24, 0);
  k_quantile1<<<8, 64, 0, stream>>>(KB, KA, QB1);

  k_bhist<<<256, 256, 0, stream>>>(coords, QB1, HIST);
  k_scan2<<<8, 256, 0, stream>>>(HIST, 64);
  k_bscatter<<<256, 256, 0, stream>>>(coords, QB1, HIST, IDX1);

  k_level2<<<512, 256, 0, stream>>>(IDX1, coords, IDXT, CM);

  k_cp2<<<8, 256, 0, stream>>>(CM, CP);
  k_selA<<<1056, 128, 0, stream>>>(CP, IND0T, C1SEL);
  k_sel1b<<<512, 64, 0, stream>>>(C1SEL, IND);

  k_db<<<4096, 256, 0, stream>>>(x, IDXT, DB);
  k_final3<<<2048, 256, 0, stream>>>(DB, IND, IND0T, outp);
}